// Round 1
// baseline (1965.368 us; speedup 1.0000x reference)
//
#include <hip/hip_runtime.h>
#include <hip/hip_bf16.h>
#include <math.h>

// Problem constants (from reference)
#define N_NODES 50000
#define E_EDGES 800000
#define EP (E_EDGES + N_NODES)   // 850000 edges incl. self-loops
#define IN_DIM 1280
#define HID 256
#define NHEAD 4
#define DHEAD 64
#define NEG_SLOPE 0.2f

// ---------------- graph build (CSR by dst, rebuilt every call) ----------------

__global__ void hist_kernel(const int* __restrict__ ei, int* __restrict__ deg) {
  int e = blockIdx.x * blockDim.x + threadIdx.x;
  if (e >= EP) return;
  int dst = (e < E_EDGES) ? ei[E_EDGES + e] : (e - E_EDGES);
  atomicAdd(&deg[dst], 1);
}

// single-block scan: deg_cursor holds degrees on entry; on exit row_ptr[0..N] is the
// exclusive scan (CSR offsets) and deg_cursor[i] = row_ptr[i] (scatter cursors).
__global__ __launch_bounds__(1024) void scan_kernel(int* __restrict__ dc, int* __restrict__ row_ptr) {
  __shared__ int wsum[16];
  int tid = threadIdx.x;
  int lane = tid & 63;
  int wid = tid >> 6;
  int running = 0;
  if (tid == 0) row_ptr[0] = 0;
  for (int base = 0; base < N_NODES; base += 1024) {
    int i = base + tid;
    int v = (i < N_NODES) ? dc[i] : 0;
    // inclusive wave scan
    int s = v;
    #pragma unroll
    for (int off = 1; off < 64; off <<= 1) {
      int t = __shfl_up(s, off);
      if (lane >= off) s += t;
    }
    if (lane == 63) wsum[wid] = s;
    __syncthreads();
    if (wid == 0 && lane < 16) {
      int w = wsum[lane];
      #pragma unroll
      for (int off = 1; off < 16; off <<= 1) {
        int t = __shfl_up(w, off);
        if (lane >= off) w += t;
      }
      wsum[lane] = w;  // inclusive scan of wave sums
    }
    __syncthreads();
    int woff = (wid > 0) ? wsum[wid - 1] : 0;
    int incl = running + woff + s;
    if (i < N_NODES) {
      row_ptr[i + 1] = incl;
      dc[i] = incl - v;  // exclusive -> cursor
    }
    running += wsum[15];
    __syncthreads();
  }
}

__global__ void scatter_kernel(const int* __restrict__ ei, int* __restrict__ cursor,
                               int* __restrict__ csr_src, int* __restrict__ csr_eid) {
  int e = blockIdx.x * blockDim.x + threadIdx.x;
  if (e >= EP) return;
  int src, dst;
  if (e < E_EDGES) { src = ei[e]; dst = ei[E_EDGES + e]; }
  else             { src = dst = e - E_EDGES; }
  int pos = atomicAdd(&cursor[dst], 1);
  csr_src[pos] = src;
  csr_eid[pos] = e;
}

// ---------------- f32 tiled GEMM: C[M,Nc] = A[M,K] @ W[K,Nc] + bias ----------------
// BM=BN=64, BK=16, 256 threads, 4x4 per thread.
__global__ __launch_bounds__(256) void gemm_bias(const float* __restrict__ A,
                                                 const float* __restrict__ W,
                                                 const float* __restrict__ bias,
                                                 float* __restrict__ C,
                                                 int M, int K, int Nc) {
  __shared__ float As[16][64];  // [k][m]
  __shared__ float Bs[16][64];  // [k][n]
  int bm = blockIdx.x * 64;
  int bn = blockIdx.y * 64;
  int tid = threadIdx.x;
  int tx = tid & 15;   // n-group
  int ty = tid >> 4;   // m-group
  float acc[4][4] = {{0.f}};

  for (int k0 = 0; k0 < K; k0 += 16) {
    // A tile: thread t loads float4 of row r=t>>2, quad q=t&3
    int r = tid >> 2, q = tid & 3;
    float4 av = make_float4(0.f, 0.f, 0.f, 0.f);
    int arow = bm + r;
    if (arow < M) av = *(const float4*)(A + (size_t)arow * K + k0 + q * 4);
    As[q * 4 + 0][r] = av.x;
    As[q * 4 + 1][r] = av.y;
    As[q * 4 + 2][r] = av.z;
    As[q * 4 + 3][r] = av.w;
    // W tile: thread t loads float4 of k-row kk=t>>4, quad q2=t&15
    int kk = tid >> 4, q2 = tid & 15;
    float4 wv = *(const float4*)(W + (size_t)(k0 + kk) * Nc + bn + q2 * 4);
    *(float4*)&Bs[kk][q2 * 4] = wv;
    __syncthreads();
    #pragma unroll
    for (int k = 0; k < 16; ++k) {
      float4 a = *(const float4*)&As[k][ty * 4];
      float4 b = *(const float4*)&Bs[k][tx * 4];
      acc[0][0] += a.x * b.x; acc[0][1] += a.x * b.y; acc[0][2] += a.x * b.z; acc[0][3] += a.x * b.w;
      acc[1][0] += a.y * b.x; acc[1][1] += a.y * b.y; acc[1][2] += a.y * b.z; acc[1][3] += a.y * b.w;
      acc[2][0] += a.z * b.x; acc[2][1] += a.z * b.y; acc[2][2] += a.z * b.z; acc[2][3] += a.z * b.w;
      acc[3][0] += a.w * b.x; acc[3][1] += a.w * b.y; acc[3][2] += a.w * b.z; acc[3][3] += a.w * b.w;
    }
    __syncthreads();
  }
  int col = bn + tx * 4;
  float4 bv = *(const float4*)(bias + col);
  #pragma unroll
  for (int i = 0; i < 4; ++i) {
    int row = bm + ty * 4 + i;
    if (row < M) {
      float4 o;
      o.x = acc[i][0] + bv.x;
      o.y = acc[i][1] + bv.y;
      o.z = acc[i][2] + bv.z;
      o.w = acc[i][3] + bv.w;
      *(float4*)(C + (size_t)row * Nc + col) = o;
    }
  }
}

// ---------------- GATv2 layer: one wave per destination node ----------------
// Lane l owns channels 4l..4l+3 (head hgrp = l>>4, d = (4l)&63).
// pass1: logits + per-head max; pass2: denom; pass3: alpha out + aggregation,
// then bias + residual + ELU, h updated in place.
__global__ __launch_bounds__(64) void gat_layer(const float* __restrict__ xl,
                                                const float* __restrict__ xr,
                                                float* h_inout,
                                                const float* __restrict__ att,
                                                const float* __restrict__ bias,
                                                const int* __restrict__ row_ptr,
                                                const int* __restrict__ csr_src,
                                                const int* __restrict__ csr_eid,
                                                float* __restrict__ logits_ws,
                                                float* __restrict__ alpha_out) {
  int node = blockIdx.x;
  int l = threadIdx.x;       // 0..63
  int hgrp = l >> 4;         // head this lane's channels belong to
  int r0 = row_ptr[node];
  int r1 = row_ptr[node + 1];

  float4 xr4 = *(const float4*)(xr + (size_t)node * HID + l * 4);
  float4 at4 = *(const float4*)(att + l * 4);

  // ---- pass 1: logits + running max per head ----
  float mx = -INFINITY;
  for (int j = r0; j < r1; ++j) {
    int s = csr_src[j];
    float4 v = *(const float4*)(xl + (size_t)s * HID + l * 4);
    float t0 = v.x + xr4.x; t0 = (t0 > 0.f) ? t0 : NEG_SLOPE * t0;
    float t1 = v.y + xr4.y; t1 = (t1 > 0.f) ? t1 : NEG_SLOPE * t1;
    float t2 = v.z + xr4.z; t2 = (t2 > 0.f) ? t2 : NEG_SLOPE * t2;
    float t3 = v.w + xr4.w; t3 = (t3 > 0.f) ? t3 : NEG_SLOPE * t3;
    float p = t0 * at4.x + t1 * at4.y + t2 * at4.z + t3 * at4.w;
    // reduce across the 16 lanes of this head group
    p += __shfl_xor(p, 1);
    p += __shfl_xor(p, 2);
    p += __shfl_xor(p, 4);
    p += __shfl_xor(p, 8);
    if ((l & 15) == 0) logits_ws[(size_t)j * NHEAD + hgrp] = p;
    mx = fmaxf(mx, p);
  }
  __threadfence_block();  // make logits visible to re-reads below

  // ---- pass 2: denom. lane l handles head (l&3), edges j = r0 + (l>>2) + 16t ----
  float mh = __shfl(mx, (l & 3) * 16);  // max of head (l&3)
  float dacc = 0.f;
  for (int j = r0 + (l >> 2); j < r1; j += 16) {
    dacc += __expf(logits_ws[(size_t)j * NHEAD + (l & 3)] - mh);
  }
  dacc += __shfl_xor(dacc, 4);
  dacc += __shfl_xor(dacc, 8);
  dacc += __shfl_xor(dacc, 16);
  dacc += __shfl_xor(dacc, 32);
  // lane l now holds denom of head (l&3); fetch denom of my head (l>>4):
  float den = __shfl(dacc, l >> 4);
  float inv_den = 1.f / (den + 1e-16f);

  // ---- pass 3: alpha + weighted aggregation ----
  float4 acc = make_float4(0.f, 0.f, 0.f, 0.f);
  for (int j = r0; j < r1; ++j) {
    int s = csr_src[j];
    float lg = logits_ws[(size_t)j * NHEAD + hgrp];
    float alpha = __expf(lg - mx) * inv_den;
    float4 v = *(const float4*)(xl + (size_t)s * HID + l * 4);
    acc.x += alpha * v.x;
    acc.y += alpha * v.y;
    acc.z += alpha * v.z;
    acc.w += alpha * v.w;
    if ((l & 15) == 0) alpha_out[(size_t)csr_eid[j] * NHEAD + hgrp] = alpha;
  }

  // ---- epilogue: bias + residual + ELU, in-place ----
  float4 b4 = *(const float4*)(bias + l * 4);
  float4 h4 = *(const float4*)(h_inout + (size_t)node * HID + l * 4);
  float o0 = acc.x + b4.x + h4.x;
  float o1 = acc.y + b4.y + h4.y;
  float o2 = acc.z + b4.z + h4.z;
  float o3 = acc.w + b4.w + h4.w;
  o0 = (o0 > 0.f) ? o0 : (__expf(o0) - 1.f);
  o1 = (o1 > 0.f) ? o1 : (__expf(o1) - 1.f);
  o2 = (o2 > 0.f) ? o2 : (__expf(o2) - 1.f);
  o3 = (o3 > 0.f) ? o3 : (__expf(o3) - 1.f);
  float4 o = make_float4(o0, o1, o2, o3);
  *(float4*)(h_inout + (size_t)node * HID + l * 4) = o;
}

// ---------------- classifier: preds[n] = dot(h[n], clf_W) + clf_b ----------------
__global__ __launch_bounds__(64) void clf_kernel(const float* __restrict__ h,
                                                 const float* __restrict__ clf_W,
                                                 const float* __restrict__ clf_b,
                                                 float* __restrict__ preds) {
  int n = blockIdx.x;
  int l = threadIdx.x;
  float4 v = *(const float4*)(h + (size_t)n * HID + l * 4);
  float4 w = *(const float4*)(clf_W + l * 4);
  float s = v.x * w.x + v.y * w.y + v.z * w.z + v.w * w.w;
  s += __shfl_xor(s, 1);
  s += __shfl_xor(s, 2);
  s += __shfl_xor(s, 4);
  s += __shfl_xor(s, 8);
  s += __shfl_xor(s, 16);
  s += __shfl_xor(s, 32);
  if (l == 0) preds[n] = s + clf_b[0];
}

// ---------------- launcher ----------------
extern "C" void kernel_launch(void* const* d_in, const int* in_sizes, int n_in,
                              void* d_out, int out_size, void* d_ws, size_t ws_size,
                              hipStream_t stream) {
  const float* x     = (const float*)d_in[0];
  const int*   ei    = (const int*)d_in[1];
  const float* enc_W = (const float*)d_in[2];
  const float* enc_b = (const float*)d_in[3];
  const float* Wl0   = (const float*)d_in[4];
  const float* bl0   = (const float*)d_in[5];
  const float* Wr0   = (const float*)d_in[6];
  const float* br0   = (const float*)d_in[7];
  const float* att0  = (const float*)d_in[8];
  const float* bias0 = (const float*)d_in[9];
  const float* Wl1   = (const float*)d_in[10];
  const float* bl1   = (const float*)d_in[11];
  const float* Wr1   = (const float*)d_in[12];
  const float* br1   = (const float*)d_in[13];
  const float* att1  = (const float*)d_in[14];
  const float* bias1 = (const float*)d_in[15];
  const float* clf_W = (const float*)d_in[16];
  const float* clf_b = (const float*)d_in[17];

  float* preds  = (float*)d_out;
  float* alpha0 = preds + N_NODES;
  float* alpha1 = alpha0 + (size_t)EP * NHEAD;

  // workspace carve-up (~175 MB total)
  float* h      = (float*)d_ws;                       // N*HID
  float* xl     = h  + (size_t)N_NODES * HID;         // N*HID
  float* xr     = xl + (size_t)N_NODES * HID;         // N*HID
  float* logits = xr + (size_t)N_NODES * HID;         // EP*NHEAD
  int* row_ptr  = (int*)(logits + (size_t)EP * NHEAD);// N+1
  int* cursor   = row_ptr + (N_NODES + 1);            // N
  int* csr_src  = cursor + N_NODES;                   // EP
  int* csr_eid  = csr_src + EP;                       // EP

  // --- CSR build ---
  hipMemsetAsync(cursor, 0, N_NODES * sizeof(int), stream);
  int eb = 256, eg = (EP + eb - 1) / eb;
  hist_kernel<<<eg, eb, 0, stream>>>(ei, cursor);
  scan_kernel<<<1, 1024, 0, stream>>>(cursor, row_ptr);
  scatter_kernel<<<eg, eb, 0, stream>>>(ei, cursor, csr_src, csr_eid);

  dim3 gB(256);
  dim3 gTiles((N_NODES + 63) / 64, HID / 64);

  // encoder
  gemm_bias<<<gTiles, gB, 0, stream>>>(x, enc_W, enc_b, h, N_NODES, IN_DIM, HID);

  // layer 0
  gemm_bias<<<gTiles, gB, 0, stream>>>(h, Wl0, bl0, xl, N_NODES, HID, HID);
  gemm_bias<<<gTiles, gB, 0, stream>>>(h, Wr0, br0, xr, N_NODES, HID, HID);
  gat_layer<<<N_NODES, 64, 0, stream>>>(xl, xr, h, att0, bias0, row_ptr, csr_src, csr_eid, logits, alpha0);

  // layer 1
  gemm_bias<<<gTiles, gB, 0, stream>>>(h, Wl1, bl1, xl, N_NODES, HID, HID);
  gemm_bias<<<gTiles, gB, 0, stream>>>(h, Wr1, br1, xr, N_NODES, HID, HID);
  gat_layer<<<N_NODES, 64, 0, stream>>>(xl, xr, h, att1, bias1, row_ptr, csr_src, csr_eid, logits, alpha1);

  // classifier
  clf_kernel<<<N_NODES, 64, 0, stream>>>(h, clf_W, clf_b, preds);
}

// Round 2
// 1352.026 us; speedup vs baseline: 1.4536x; 1.4536x over previous
//
#include <hip/hip_runtime.h>
#include <hip/hip_bf16.h>
#include <math.h>

// Problem constants (from reference)
#define N_NODES 50000
#define E_EDGES 800000
#define EP (E_EDGES + N_NODES)   // 850000 edges incl. self-loops
#define IN_DIM 1280
#define HID 256
#define NHEAD 4
#define DHEAD 64
#define NEG_SLOPE 0.2f

typedef unsigned short ushort_t;
typedef __attribute__((ext_vector_type(8))) short short8;     // 8 bf16 (4 VGPRs)
typedef __attribute__((ext_vector_type(4))) float floatx4;    // MFMA acc

__device__ __forceinline__ float bf2f(ushort_t h) {
  return __uint_as_float(((unsigned)h) << 16);
}
// truncation split: x = hi + lo + O(2^-16 x)
__device__ __forceinline__ void split_bf16(float x, ushort_t& hi, ushort_t& lo) {
  unsigned u = __float_as_uint(x);
  hi = (ushort_t)(u >> 16);
  float rem = x - __uint_as_float(u & 0xFFFF0000u);
  lo = (ushort_t)(__float_as_uint(rem) >> 16);
}

__device__ __forceinline__ void gload_lds16(const void* g, void* l) {
  __builtin_amdgcn_global_load_lds(
      (const __attribute__((address_space(1))) unsigned int*)g,
      (__attribute__((address_space(3))) unsigned int*)l, 16, 0, 0);
}

// ---------------- graph build (CSR by dst, rebuilt every call) ----------------

__global__ void hist_kernel(const int* __restrict__ ei, int* __restrict__ deg) {
  int e = blockIdx.x * blockDim.x + threadIdx.x;
  if (e >= EP) return;
  int dst = (e < E_EDGES) ? ei[E_EDGES + e] : (e - E_EDGES);
  atomicAdd(&deg[dst], 1);
}

__global__ __launch_bounds__(1024) void scan_kernel(int* __restrict__ dc, int* __restrict__ row_ptr) {
  __shared__ int wsum[16];
  int tid = threadIdx.x;
  int lane = tid & 63;
  int wid = tid >> 6;
  int running = 0;
  if (tid == 0) row_ptr[0] = 0;
  for (int base = 0; base < N_NODES; base += 1024) {
    int i = base + tid;
    int v = (i < N_NODES) ? dc[i] : 0;
    int s = v;
    #pragma unroll
    for (int off = 1; off < 64; off <<= 1) {
      int t = __shfl_up(s, off);
      if (lane >= off) s += t;
    }
    if (lane == 63) wsum[wid] = s;
    __syncthreads();
    if (wid == 0 && lane < 16) {
      int w = wsum[lane];
      #pragma unroll
      for (int off = 1; off < 16; off <<= 1) {
        int t = __shfl_up(w, off);
        if (lane >= off) w += t;
      }
      wsum[lane] = w;
    }
    __syncthreads();
    int woff = (wid > 0) ? wsum[wid - 1] : 0;
    int incl = running + woff + s;
    if (i < N_NODES) {
      row_ptr[i + 1] = incl;
      dc[i] = incl - v;
    }
    running += wsum[15];
    __syncthreads();
  }
}

__global__ void scatter_kernel(const int* __restrict__ ei, int* __restrict__ cursor,
                               int* __restrict__ csr_src, int* __restrict__ csr_eid) {
  int e = blockIdx.x * blockDim.x + threadIdx.x;
  if (e >= EP) return;
  int src, dst;
  if (e < E_EDGES) { src = ei[e]; dst = ei[E_EDGES + e]; }
  else             { src = dst = e - E_EDGES; }
  int pos = atomicAdd(&cursor[dst], 1);
  csr_src[pos] = src;
  csr_eid[pos] = e;
}

// ---------------- weight transpose + bf16 split: W[K][Nc] -> WhT/WlT [Nc][K] ----------------
__global__ void wsplit_kernel(const float* __restrict__ W, ushort_t* __restrict__ WhT,
                              ushort_t* __restrict__ WlT, int K, int Nc) {
  int idx = blockIdx.x * blockDim.x + threadIdx.x;
  if (idx >= K * Nc) return;
  int k = idx / Nc, n = idx - k * Nc;
  ushort_t hi, lo;
  split_bf16(W[idx], hi, lo);
  WhT[(size_t)n * K + k] = hi;
  WlT[(size_t)n * K + k] = lo;
}

// ---------------- MFMA GEMM: C[M,Nc] = A[M,K](fp32) @ W + bias ----------------
// A split to bf16 hi/lo in-register during staging; B pre-split/transposed [Nc][K] bf16.
// 128x128 tile, BK=32, 4 waves, each wave 64x64 via 4x4 mfma_f32_16x16x32_bf16,
// 3-term split product per tile pair.
__global__ __launch_bounds__(256) void gemm_mfma(const float* __restrict__ A,
                                                 const ushort_t* __restrict__ BhT,
                                                 const ushort_t* __restrict__ BlT,
                                                 const float* __restrict__ bias,
                                                 float* __restrict__ C,
                                                 int M, int K, int Nc) {
  __shared__ ushort_t sAh[128 * 32];
  __shared__ ushort_t sAl[128 * 32];
  __shared__ ushort_t sBh[128 * 32];
  __shared__ ushort_t sBl[128 * 32];

  const int tid = threadIdx.x;
  const int lane = tid & 63;
  const int w = tid >> 6;            // wave 0..3
  const int wm = w >> 1, wn = w & 1; // 2x2 wave grid over the 128x128 tile
  const int bm = blockIdx.x * 128;
  const int bn = blockIdx.y * 128;
  const int r = lane & 15, q = lane >> 4;

  // A staging: thread owns row ar=tid>>1, half=tid&1 -> 16 consecutive floats (64B)
  const int ar = tid >> 1;
  const int ahalf = tid & 1;
  int arow = bm + ar; if (arow >= M) arow = M - 1;   // clamp; garbage rows never stored
  const float* aptr = A + (size_t)arow * K + ahalf * 16;

  floatx4 acc[4][4];
  #pragma unroll
  for (int i = 0; i < 4; ++i)
    #pragma unroll
    for (int j = 0; j < 4; ++j) acc[i][j] = (floatx4)(0.0f);

  // B staging entry precompute: entries e0=tid, e1=tid+256 of 512x16B per tile
  const int e0 = tid, e1 = tid + 256;
  const size_t b0off = (size_t)(bn + (e0 >> 2)) * K + (e0 & 3) * 8;
  const size_t b1off = (size_t)(bn + (e1 >> 2)) * K + (e1 & 3) * 8;

  for (int k0 = 0; k0 < K; k0 += 32) {
    // --- async B tile loads (bf16, 16B per lane, LDS = wave-uniform base + lane*16) ---
    gload_lds16(BhT + b0off + k0, &sBh[e0 * 8]);
    gload_lds16(BhT + b1off + k0, &sBh[e1 * 8]);
    gload_lds16(BlT + b0off + k0, &sBl[e0 * 8]);
    gload_lds16(BlT + b1off + k0, &sBl[e1 * 8]);

    // --- A tile: 4x float4 load, split to hi/lo bf16, ds_write ---
    float va[16];
    *(float4*)&va[0]  = *(const float4*)(aptr + k0);
    *(float4*)&va[4]  = *(const float4*)(aptr + k0 + 4);
    *(float4*)&va[8]  = *(const float4*)(aptr + k0 + 8);
    *(float4*)&va[12] = *(const float4*)(aptr + k0 + 12);
    short8 h0, h1, l0, l1;
    #pragma unroll
    for (int i = 0; i < 8; ++i) {
      ushort_t hi, lo;
      split_bf16(va[i], hi, lo);
      h0[i] = (short)hi; l0[i] = (short)lo;
    }
    #pragma unroll
    for (int i = 0; i < 8; ++i) {
      ushort_t hi, lo;
      split_bf16(va[8 + i], hi, lo);
      h1[i] = (short)hi; l1[i] = (short)lo;
    }
    int aoff = ar * 32 + ahalf * 16;
    *(short8*)&sAh[aoff] = h0;  *(short8*)&sAh[aoff + 8] = h1;
    *(short8*)&sAl[aoff] = l0;  *(short8*)&sAl[aoff + 8] = l1;

    __syncthreads();  // drains vmcnt (B async) + lgkm (A writes)

    // --- fragments + MFMA ---
    short8 ah[4], al[4], bh[4], bl[4];
    #pragma unroll
    for (int i = 0; i < 4; ++i) {
      int arow_l = (wm * 64 + i * 16 + r) * 32 + q * 8;
      int brow_l = (wn * 64 + i * 16 + r) * 32 + q * 8;
      ah[i] = *(const short8*)&sAh[arow_l];
      al[i] = *(const short8*)&sAl[arow_l];
      bh[i] = *(const short8*)&sBh[brow_l];
      bl[i] = *(const short8*)&sBl[brow_l];
    }
    #pragma unroll
    for (int i = 0; i < 4; ++i)
      #pragma unroll
      for (int j = 0; j < 4; ++j) {
        acc[i][j] = __builtin_amdgcn_mfma_f32_16x16x32_bf16(ah[i], bh[j], acc[i][j], 0, 0, 0);
        acc[i][j] = __builtin_amdgcn_mfma_f32_16x16x32_bf16(ah[i], bl[j], acc[i][j], 0, 0, 0);
        acc[i][j] = __builtin_amdgcn_mfma_f32_16x16x32_bf16(al[i], bh[j], acc[i][j], 0, 0, 0);
      }
    __syncthreads();  // protect LDS from next iteration's overwrite
  }

  // --- epilogue: bias add + store. C/D layout: col=lane&15, row=(lane>>4)*4+reg ---
  #pragma unroll
  for (int j = 0; j < 4; ++j) {
    int col = bn + wn * 64 + j * 16 + r;
    float bv = bias[col];
    #pragma unroll
    for (int i = 0; i < 4; ++i) {
      int row0 = bm + wm * 64 + i * 16 + q * 4;
      #pragma unroll
      for (int rr = 0; rr < 4; ++rr) {
        int row = row0 + rr;
        if (row < M) C[(size_t)row * Nc + col] = acc[i][j][rr] + bv;
      }
    }
  }
}

// ---------------- GATv2 layer: one wave per destination node ----------------
__global__ __launch_bounds__(64) void gat_layer(const float* __restrict__ xl,
                                                const float* __restrict__ xr,
                                                float* h_inout,
                                                const float* __restrict__ att,
                                                const float* __restrict__ bias,
                                                const int* __restrict__ row_ptr,
                                                const int* __restrict__ csr_src,
                                                const int* __restrict__ csr_eid,
                                                float* __restrict__ logits_ws,
                                                float* __restrict__ alpha_out) {
  int node = blockIdx.x;
  int l = threadIdx.x;
  int hgrp = l >> 4;
  int r0 = row_ptr[node];
  int r1 = row_ptr[node + 1];

  float4 xr4 = *(const float4*)(xr + (size_t)node * HID + l * 4);
  float4 at4 = *(const float4*)(att + l * 4);

  float mx = -INFINITY;
  for (int j = r0; j < r1; ++j) {
    int s = csr_src[j];
    float4 v = *(const float4*)(xl + (size_t)s * HID + l * 4);
    float t0 = v.x + xr4.x; t0 = (t0 > 0.f) ? t0 : NEG_SLOPE * t0;
    float t1 = v.y + xr4.y; t1 = (t1 > 0.f) ? t1 : NEG_SLOPE * t1;
    float t2 = v.z + xr4.z; t2 = (t2 > 0.f) ? t2 : NEG_SLOPE * t2;
    float t3 = v.w + xr4.w; t3 = (t3 > 0.f) ? t3 : NEG_SLOPE * t3;
    float p = t0 * at4.x + t1 * at4.y + t2 * at4.z + t3 * at4.w;
    p += __shfl_xor(p, 1);
    p += __shfl_xor(p, 2);
    p += __shfl_xor(p, 4);
    p += __shfl_xor(p, 8);
    if ((l & 15) == 0) logits_ws[(size_t)j * NHEAD + hgrp] = p;
    mx = fmaxf(mx, p);
  }
  __threadfence_block();

  float mh = __shfl(mx, (l & 3) * 16);
  float dacc = 0.f;
  for (int j = r0 + (l >> 2); j < r1; j += 16) {
    dacc += __expf(logits_ws[(size_t)j * NHEAD + (l & 3)] - mh);
  }
  dacc += __shfl_xor(dacc, 4);
  dacc += __shfl_xor(dacc, 8);
  dacc += __shfl_xor(dacc, 16);
  dacc += __shfl_xor(dacc, 32);
  float den = __shfl(dacc, l >> 4);
  float inv_den = 1.f / (den + 1e-16f);

  float4 acc = make_float4(0.f, 0.f, 0.f, 0.f);
  for (int j = r0; j < r1; ++j) {
    int s = csr_src[j];
    float lg = logits_ws[(size_t)j * NHEAD + hgrp];
    float alpha = __expf(lg - mx) * inv_den;
    float4 v = *(const float4*)(xl + (size_t)s * HID + l * 4);
    acc.x += alpha * v.x;
    acc.y += alpha * v.y;
    acc.z += alpha * v.z;
    acc.w += alpha * v.w;
    if ((l & 15) == 0) alpha_out[(size_t)csr_eid[j] * NHEAD + hgrp] = alpha;
  }

  float4 b4 = *(const float4*)(bias + l * 4);
  float4 h4 = *(const float4*)(h_inout + (size_t)node * HID + l * 4);
  float o0 = acc.x + b4.x + h4.x;
  float o1 = acc.y + b4.y + h4.y;
  float o2 = acc.z + b4.z + h4.z;
  float o3 = acc.w + b4.w + h4.w;
  o0 = (o0 > 0.f) ? o0 : (__expf(o0) - 1.f);
  o1 = (o1 > 0.f) ? o1 : (__expf(o1) - 1.f);
  o2 = (o2 > 0.f) ? o2 : (__expf(o2) - 1.f);
  o3 = (o3 > 0.f) ? o3 : (__expf(o3) - 1.f);
  *(float4*)(h_inout + (size_t)node * HID + l * 4) = make_float4(o0, o1, o2, o3);
}

// ---------------- classifier ----------------
__global__ __launch_bounds__(64) void clf_kernel(const float* __restrict__ h,
                                                 const float* __restrict__ clf_W,
                                                 const float* __restrict__ clf_b,
                                                 float* __restrict__ preds) {
  int n = blockIdx.x;
  int l = threadIdx.x;
  float4 v = *(const float4*)(h + (size_t)n * HID + l * 4);
  float4 w = *(const float4*)(clf_W + l * 4);
  float s = v.x * w.x + v.y * w.y + v.z * w.z + v.w * w.w;
  s += __shfl_xor(s, 1);
  s += __shfl_xor(s, 2);
  s += __shfl_xor(s, 4);
  s += __shfl_xor(s, 8);
  s += __shfl_xor(s, 16);
  s += __shfl_xor(s, 32);
  if (l == 0) preds[n] = s + clf_b[0];
}

// ---------------- launcher ----------------
static inline char* carve(char*& p, size_t bytes) {
  char* ret = p;
  p += (bytes + 255) & ~(size_t)255;
  return ret;
}

extern "C" void kernel_launch(void* const* d_in, const int* in_sizes, int n_in,
                              void* d_out, int out_size, void* d_ws, size_t ws_size,
                              hipStream_t stream) {
  const float* x     = (const float*)d_in[0];
  const int*   ei    = (const int*)d_in[1];
  const float* enc_W = (const float*)d_in[2];
  const float* enc_b = (const float*)d_in[3];
  const float* Wl0   = (const float*)d_in[4];
  const float* bl0   = (const float*)d_in[5];
  const float* Wr0   = (const float*)d_in[6];
  const float* br0   = (const float*)d_in[7];
  const float* att0  = (const float*)d_in[8];
  const float* bias0 = (const float*)d_in[9];
  const float* Wl1   = (const float*)d_in[10];
  const float* bl1   = (const float*)d_in[11];
  const float* Wr1   = (const float*)d_in[12];
  const float* br1   = (const float*)d_in[13];
  const float* att1  = (const float*)d_in[14];
  const float* bias1 = (const float*)d_in[15];
  const float* clf_W = (const float*)d_in[16];
  const float* clf_b = (const float*)d_in[17];

  float* preds  = (float*)d_out;
  float* alpha0 = preds + N_NODES;
  float* alpha1 = alpha0 + (size_t)EP * NHEAD;

  char* p = (char*)d_ws;
  float* h      = (float*)carve(p, (size_t)N_NODES * HID * 4);
  float* xl     = (float*)carve(p, (size_t)N_NODES * HID * 4);
  float* xr     = (float*)carve(p, (size_t)N_NODES * HID * 4);
  float* logits = (float*)carve(p, (size_t)EP * NHEAD * 4);
  int* row_ptr  = (int*)carve(p, (size_t)(N_NODES + 1) * 4);
  int* cursor   = (int*)carve(p, (size_t)N_NODES * 4);
  int* csr_src  = (int*)carve(p, (size_t)EP * 4);
  int* csr_eid  = (int*)carve(p, (size_t)EP * 4);
  ushort_t* encWh = (ushort_t*)carve(p, (size_t)IN_DIM * HID * 2);
  ushort_t* encWl = (ushort_t*)carve(p, (size_t)IN_DIM * HID * 2);
  ushort_t* Wl0h  = (ushort_t*)carve(p, (size_t)HID * HID * 2);
  ushort_t* Wl0l  = (ushort_t*)carve(p, (size_t)HID * HID * 2);
  ushort_t* Wr0h  = (ushort_t*)carve(p, (size_t)HID * HID * 2);
  ushort_t* Wr0l  = (ushort_t*)carve(p, (size_t)HID * HID * 2);
  ushort_t* Wl1h  = (ushort_t*)carve(p, (size_t)HID * HID * 2);
  ushort_t* Wl1l  = (ushort_t*)carve(p, (size_t)HID * HID * 2);
  ushort_t* Wr1h  = (ushort_t*)carve(p, (size_t)HID * HID * 2);
  ushort_t* Wr1l  = (ushort_t*)carve(p, (size_t)HID * HID * 2);

  // --- CSR build ---
  hipMemsetAsync(cursor, 0, N_NODES * sizeof(int), stream);
  int eb = 256, eg = (EP + eb - 1) / eb;
  hist_kernel<<<eg, eb, 0, stream>>>(ei, cursor);
  scan_kernel<<<1, 1024, 0, stream>>>(cursor, row_ptr);
  scatter_kernel<<<eg, eb, 0, stream>>>(ei, cursor, csr_src, csr_eid);

  // --- weight preprocessing (transpose + bf16 split) ---
  int wthreads = 256;
  wsplit_kernel<<<(IN_DIM * HID + wthreads - 1) / wthreads, wthreads, 0, stream>>>(enc_W, encWh, encWl, IN_DIM, HID);
  wsplit_kernel<<<(HID * HID + wthreads - 1) / wthreads, wthreads, 0, stream>>>(Wl0, Wl0h, Wl0l, HID, HID);
  wsplit_kernel<<<(HID * HID + wthreads - 1) / wthreads, wthreads, 0, stream>>>(Wr0, Wr0h, Wr0l, HID, HID);
  wsplit_kernel<<<(HID * HID + wthreads - 1) / wthreads, wthreads, 0, stream>>>(Wl1, Wl1h, Wl1l, HID, HID);
  wsplit_kernel<<<(HID * HID + wthreads - 1) / wthreads, wthreads, 0, stream>>>(Wr1, Wr1h, Wr1l, HID, HID);

  dim3 gGemm((N_NODES + 127) / 128, HID / 128);
  dim3 bGemm(256);

  // encoder: h = x @ enc_W + enc_b
  gemm_mfma<<<gGemm, bGemm, 0, stream>>>(x, encWh, encWl, enc_b, h, N_NODES, IN_DIM, HID);

  // layer 0
  gemm_mfma<<<gGemm, bGemm, 0, stream>>>(h, Wl0h, Wl0l, bl0, xl, N_NODES, HID, HID);
  gemm_mfma<<<gGemm, bGemm, 0, stream>>>(h, Wr0h, Wr0l, br0, xr, N_NODES, HID, HID);
  gat_layer<<<N_NODES, 64, 0, stream>>>(xl, xr, h, att0, bias0, row_ptr, csr_src, csr_eid, logits, alpha0);

  // layer 1
  gemm_mfma<<<gGemm, bGemm, 0, stream>>>(h, Wl1h, Wl1l, bl1, xl, N_NODES, HID, HID);
  gemm_mfma<<<gGemm, bGemm, 0, stream>>>(h, Wr1h, Wr1l, br1, xr, N_NODES, HID, HID);
  gat_layer<<<N_NODES, 64, 0, stream>>>(xl, xr, h, att1, bias1, row_ptr, csr_src, csr_eid, logits, alpha1);

  // classifier
  clf_kernel<<<N_NODES, 64, 0, stream>>>(h, clf_W, clf_b, preds);
}

// Round 3
// 1145.121 us; speedup vs baseline: 1.7163x; 1.1807x over previous
//
#include <hip/hip_runtime.h>
#include <hip/hip_bf16.h>
#include <math.h>

// Problem constants (from reference)
#define N_NODES 50000
#define E_EDGES 800000
#define EP (E_EDGES + N_NODES)   // 850000 edges incl. self-loops
#define IN_DIM 1280
#define HID 256
#define NHEAD 4
#define DHEAD 64
#define NEG_SLOPE 0.2f

typedef unsigned short ushort_t;
typedef __attribute__((ext_vector_type(8))) short short8;     // 8 bf16 (4 VGPRs)
typedef __attribute__((ext_vector_type(4))) float floatx4;    // MFMA acc

__device__ __forceinline__ float bf2f(ushort_t h) {
  return __uint_as_float(((unsigned)h) << 16);
}
// truncation split: x = hi + lo + O(2^-16 x)
__device__ __forceinline__ void split_bf16(float x, ushort_t& hi, ushort_t& lo) {
  unsigned u = __float_as_uint(x);
  hi = (ushort_t)(u >> 16);
  float rem = x - __uint_as_float(u & 0xFFFF0000u);
  lo = (ushort_t)(__float_as_uint(rem) >> 16);
}

__device__ __forceinline__ void gload_lds16(const void* g, void* l) {
  __builtin_amdgcn_global_load_lds(
      (const __attribute__((address_space(1))) unsigned int*)g,
      (__attribute__((address_space(3))) unsigned int*)l, 16, 0, 0);
}

// ---------------- graph build (CSR by dst, rebuilt every call) ----------------

__global__ void hist_kernel(const int* __restrict__ ei, int* __restrict__ deg) {
  int e = blockIdx.x * blockDim.x + threadIdx.x;
  if (e >= EP) return;
  int dst = (e < E_EDGES) ? ei[E_EDGES + e] : (e - E_EDGES);
  atomicAdd(&deg[dst], 1);
}

__global__ __launch_bounds__(1024) void scan_kernel(int* __restrict__ dc, int* __restrict__ row_ptr) {
  __shared__ int wsum[16];
  int tid = threadIdx.x;
  int lane = tid & 63;
  int wid = tid >> 6;
  int running = 0;
  if (tid == 0) row_ptr[0] = 0;
  for (int base = 0; base < N_NODES; base += 1024) {
    int i = base + tid;
    int v = (i < N_NODES) ? dc[i] : 0;
    int s = v;
    #pragma unroll
    for (int off = 1; off < 64; off <<= 1) {
      int t = __shfl_up(s, off);
      if (lane >= off) s += t;
    }
    if (lane == 63) wsum[wid] = s;
    __syncthreads();
    if (wid == 0 && lane < 16) {
      int w = wsum[lane];
      #pragma unroll
      for (int off = 1; off < 16; off <<= 1) {
        int t = __shfl_up(w, off);
        if (lane >= off) w += t;
      }
      wsum[lane] = w;
    }
    __syncthreads();
    int woff = (wid > 0) ? wsum[wid - 1] : 0;
    int incl = running + woff + s;
    if (i < N_NODES) {
      row_ptr[i + 1] = incl;
      dc[i] = incl - v;
    }
    running += wsum[15];
    __syncthreads();
  }
}

__global__ void scatter_kernel(const int* __restrict__ ei, int* __restrict__ cursor,
                               int* __restrict__ csr_src, int* __restrict__ csr_eid) {
  int e = blockIdx.x * blockDim.x + threadIdx.x;
  if (e >= EP) return;
  int src, dst;
  if (e < E_EDGES) { src = ei[e]; dst = ei[E_EDGES + e]; }
  else             { src = dst = e - E_EDGES; }
  int pos = atomicAdd(&cursor[dst], 1);
  csr_src[pos] = src;
  csr_eid[pos] = e;
}

// ---------------- weight transpose + bf16 split: W[K][Nc] -> WhT/WlT [Nc][K] ----------------
__global__ void wsplit_kernel(const float* __restrict__ W, ushort_t* __restrict__ WhT,
                              ushort_t* __restrict__ WlT, int K, int Nc) {
  int idx = blockIdx.x * blockDim.x + threadIdx.x;
  if (idx >= K * Nc) return;
  int k = idx / Nc, n = idx - k * Nc;
  ushort_t hi, lo;
  split_bf16(W[idx], hi, lo);
  WhT[(size_t)n * K + k] = hi;
  WlT[(size_t)n * K + k] = lo;
}

// ---------------- MFMA GEMM: C[M,Nc] = A[M,K](fp32) @ W + bias ----------------
__global__ __launch_bounds__(256) void gemm_mfma(const float* __restrict__ A,
                                                 const ushort_t* __restrict__ BhT,
                                                 const ushort_t* __restrict__ BlT,
                                                 const float* __restrict__ bias,
                                                 float* __restrict__ C,
                                                 int M, int K, int Nc) {
  __shared__ ushort_t sAh[128 * 32];
  __shared__ ushort_t sAl[128 * 32];
  __shared__ ushort_t sBh[128 * 32];
  __shared__ ushort_t sBl[128 * 32];

  const int tid = threadIdx.x;
  const int lane = tid & 63;
  const int w = tid >> 6;            // wave 0..3
  const int wm = w >> 1, wn = w & 1; // 2x2 wave grid over the 128x128 tile
  const int bm = blockIdx.x * 128;
  const int bn = blockIdx.y * 128;
  const int r = lane & 15, q = lane >> 4;

  const int ar = tid >> 1;
  const int ahalf = tid & 1;
  int arow = bm + ar; if (arow >= M) arow = M - 1;   // clamp; garbage rows never stored
  const float* aptr = A + (size_t)arow * K + ahalf * 16;

  floatx4 acc[4][4];
  #pragma unroll
  for (int i = 0; i < 4; ++i)
    #pragma unroll
    for (int j = 0; j < 4; ++j) acc[i][j] = (floatx4)(0.0f);

  const int e0 = tid, e1 = tid + 256;
  const size_t b0off = (size_t)(bn + (e0 >> 2)) * K + (e0 & 3) * 8;
  const size_t b1off = (size_t)(bn + (e1 >> 2)) * K + (e1 & 3) * 8;

  for (int k0 = 0; k0 < K; k0 += 32) {
    gload_lds16(BhT + b0off + k0, &sBh[e0 * 8]);
    gload_lds16(BhT + b1off + k0, &sBh[e1 * 8]);
    gload_lds16(BlT + b0off + k0, &sBl[e0 * 8]);
    gload_lds16(BlT + b1off + k0, &sBl[e1 * 8]);

    float va[16];
    *(float4*)&va[0]  = *(const float4*)(aptr + k0);
    *(float4*)&va[4]  = *(const float4*)(aptr + k0 + 4);
    *(float4*)&va[8]  = *(const float4*)(aptr + k0 + 8);
    *(float4*)&va[12] = *(const float4*)(aptr + k0 + 12);
    short8 h0, h1, l0, l1;
    #pragma unroll
    for (int i = 0; i < 8; ++i) {
      ushort_t hi, lo;
      split_bf16(va[i], hi, lo);
      h0[i] = (short)hi; l0[i] = (short)lo;
    }
    #pragma unroll
    for (int i = 0; i < 8; ++i) {
      ushort_t hi, lo;
      split_bf16(va[8 + i], hi, lo);
      h1[i] = (short)hi; l1[i] = (short)lo;
    }
    int aoff = ar * 32 + ahalf * 16;
    *(short8*)&sAh[aoff] = h0;  *(short8*)&sAh[aoff + 8] = h1;
    *(short8*)&sAl[aoff] = l0;  *(short8*)&sAl[aoff + 8] = l1;

    __syncthreads();

    short8 ah[4], al[4], bh[4], bl[4];
    #pragma unroll
    for (int i = 0; i < 4; ++i) {
      int arow_l = (wm * 64 + i * 16 + r) * 32 + q * 8;
      int brow_l = (wn * 64 + i * 16 + r) * 32 + q * 8;
      ah[i] = *(const short8*)&sAh[arow_l];
      al[i] = *(const short8*)&sAl[arow_l];
      bh[i] = *(const short8*)&sBh[brow_l];
      bl[i] = *(const short8*)&sBl[brow_l];
    }
    #pragma unroll
    for (int i = 0; i < 4; ++i)
      #pragma unroll
      for (int j = 0; j < 4; ++j) {
        acc[i][j] = __builtin_amdgcn_mfma_f32_16x16x32_bf16(ah[i], bh[j], acc[i][j], 0, 0, 0);
        acc[i][j] = __builtin_amdgcn_mfma_f32_16x16x32_bf16(ah[i], bl[j], acc[i][j], 0, 0, 0);
        acc[i][j] = __builtin_amdgcn_mfma_f32_16x16x32_bf16(al[i], bh[j], acc[i][j], 0, 0, 0);
      }
    __syncthreads();
  }

  #pragma unroll
  for (int j = 0; j < 4; ++j) {
    int col = bn + wn * 64 + j * 16 + r;
    float bv = bias[col];
    #pragma unroll
    for (int i = 0; i < 4; ++i) {
      int row0 = bm + wm * 64 + i * 16 + q * 4;
      #pragma unroll
      for (int rr = 0; rr < 4; ++rr) {
        int row = row0 + rr;
        if (row < M) C[(size_t)row * Nc + col] = acc[i][j][rr] + bv;
      }
    }
  }
}

// ---------------- GATv2 layer: one wave per destination node, single-gather ----------------
// Online softmax: per edge compute logit (16-lane reduce), update running (m, den, acc)
// with rescaling — xl[src] is gathered exactly ONCE per edge. Alpha pass re-reads only
// the small logits buffer.
__global__ __launch_bounds__(64) void gat_layer(const float* __restrict__ xl,
                                                const float* __restrict__ xr,
                                                float* h_inout,
                                                const float* __restrict__ att,
                                                const float* __restrict__ bias,
                                                const int* __restrict__ row_ptr,
                                                const int* __restrict__ csr_src,
                                                const int* __restrict__ csr_eid,
                                                float* __restrict__ logits_ws,
                                                float* __restrict__ alpha_out) {
  int node = blockIdx.x;
  int l = threadIdx.x;       // 0..63
  int hgrp = l >> 4;         // head this lane's channels belong to
  int r0 = row_ptr[node];
  int r1 = row_ptr[node + 1];

  float4 xr4 = *(const float4*)(xr + (size_t)node * HID + l * 4);
  float4 at4 = *(const float4*)(att + l * 4);

  // ---- single pass: logits + online softmax + weighted aggregation ----
  float m = -INFINITY;
  float den = 0.f;
  float4 acc = make_float4(0.f, 0.f, 0.f, 0.f);
  for (int j = r0; j < r1; ++j) {
    int s = csr_src[j];
    float4 v = *(const float4*)(xl + (size_t)s * HID + l * 4);
    float t0 = v.x + xr4.x; t0 = (t0 > 0.f) ? t0 : NEG_SLOPE * t0;
    float t1 = v.y + xr4.y; t1 = (t1 > 0.f) ? t1 : NEG_SLOPE * t1;
    float t2 = v.z + xr4.z; t2 = (t2 > 0.f) ? t2 : NEG_SLOPE * t2;
    float t3 = v.w + xr4.w; t3 = (t3 > 0.f) ? t3 : NEG_SLOPE * t3;
    float p = t0 * at4.x + t1 * at4.y + t2 * at4.z + t3 * at4.w;
    // reduce across the 16 lanes of this head group -> all 16 lanes hold full logit
    p += __shfl_xor(p, 1);
    p += __shfl_xor(p, 2);
    p += __shfl_xor(p, 4);
    p += __shfl_xor(p, 8);
    if ((l & 15) == 0) logits_ws[(size_t)j * NHEAD + hgrp] = p;
    // online softmax update (m starts at -inf: exp(-inf - p) == 0, so first edge
    // initializes den=w, acc=w*v exactly)
    float m_new = fmaxf(m, p);
    float scale = __expf(m - m_new);
    float wgt = __expf(p - m_new);
    den = den * scale + wgt;
    acc.x = acc.x * scale + wgt * v.x;
    acc.y = acc.y * scale + wgt * v.y;
    acc.z = acc.z * scale + wgt * v.z;
    acc.w = acc.w * scale + wgt * v.w;
    m = m_new;
  }
  float inv_den = 1.f / (den + 1e-16f);

  // ---- epilogue: out = acc/den + bias + residual, ELU, in-place ----
  float4 b4 = *(const float4*)(bias + l * 4);
  float4 h4 = *(const float4*)(h_inout + (size_t)node * HID + l * 4);
  float o0 = acc.x * inv_den + b4.x + h4.x;
  float o1 = acc.y * inv_den + b4.y + h4.y;
  float o2 = acc.z * inv_den + b4.z + h4.z;
  float o3 = acc.w * inv_den + b4.w + h4.w;
  o0 = (o0 > 0.f) ? o0 : (__expf(o0) - 1.f);
  o1 = (o1 > 0.f) ? o1 : (__expf(o1) - 1.f);
  o2 = (o2 > 0.f) ? o2 : (__expf(o2) - 1.f);
  o3 = (o3 > 0.f) ? o3 : (__expf(o3) - 1.f);
  *(float4*)(h_inout + (size_t)node * HID + l * 4) = make_float4(o0, o1, o2, o3);

  __threadfence_block();  // logits writes visible before re-read

  // ---- alpha pass: lane l handles head (l&3), edges j = r0 + (l>>2) + 16t ----
  float mh = __shfl(m, (l & 3) * 16);
  float dh = __shfl(den, (l & 3) * 16);
  float invd = 1.f / (dh + 1e-16f);
  for (int j = r0 + (l >> 2); j < r1; j += 16) {
    float lg = logits_ws[(size_t)j * NHEAD + (l & 3)];
    alpha_out[(size_t)csr_eid[j] * NHEAD + (l & 3)] = __expf(lg - mh) * invd;
  }
}

// ---------------- classifier ----------------
__global__ __launch_bounds__(64) void clf_kernel(const float* __restrict__ h,
                                                 const float* __restrict__ clf_W,
                                                 const float* __restrict__ clf_b,
                                                 float* __restrict__ preds) {
  int n = blockIdx.x;
  int l = threadIdx.x;
  float4 v = *(const float4*)(h + (size_t)n * HID + l * 4);
  float4 w = *(const float4*)(clf_W + l * 4);
  float s = v.x * w.x + v.y * w.y + v.z * w.z + v.w * w.w;
  s += __shfl_xor(s, 1);
  s += __shfl_xor(s, 2);
  s += __shfl_xor(s, 4);
  s += __shfl_xor(s, 8);
  s += __shfl_xor(s, 16);
  s += __shfl_xor(s, 32);
  if (l == 0) preds[n] = s + clf_b[0];
}

// ---------------- launcher ----------------
static inline char* carve(char*& p, size_t bytes) {
  char* ret = p;
  p += (bytes + 255) & ~(size_t)255;
  return ret;
}

extern "C" void kernel_launch(void* const* d_in, const int* in_sizes, int n_in,
                              void* d_out, int out_size, void* d_ws, size_t ws_size,
                              hipStream_t stream) {
  const float* x     = (const float*)d_in[0];
  const int*   ei    = (const int*)d_in[1];
  const float* enc_W = (const float*)d_in[2];
  const float* enc_b = (const float*)d_in[3];
  const float* Wl0   = (const float*)d_in[4];
  const float* bl0   = (const float*)d_in[5];
  const float* Wr0   = (const float*)d_in[6];
  const float* br0   = (const float*)d_in[7];
  const float* att0  = (const float*)d_in[8];
  const float* bias0 = (const float*)d_in[9];
  const float* Wl1   = (const float*)d_in[10];
  const float* bl1   = (const float*)d_in[11];
  const float* Wr1   = (const float*)d_in[12];
  const float* br1   = (const float*)d_in[13];
  const float* att1  = (const float*)d_in[14];
  const float* bias1 = (const float*)d_in[15];
  const float* clf_W = (const float*)d_in[16];
  const float* clf_b = (const float*)d_in[17];

  float* preds  = (float*)d_out;
  float* alpha0 = preds + N_NODES;
  float* alpha1 = alpha0 + (size_t)EP * NHEAD;

  char* p = (char*)d_ws;
  float* h      = (float*)carve(p, (size_t)N_NODES * HID * 4);
  float* xl     = (float*)carve(p, (size_t)N_NODES * HID * 4);
  float* xr     = (float*)carve(p, (size_t)N_NODES * HID * 4);
  float* logits = (float*)carve(p, (size_t)EP * NHEAD * 4);
  int* row_ptr  = (int*)carve(p, (size_t)(N_NODES + 1) * 4);
  int* cursor   = (int*)carve(p, (size_t)N_NODES * 4);
  int* csr_src  = (int*)carve(p, (size_t)EP * 4);
  int* csr_eid  = (int*)carve(p, (size_t)EP * 4);
  ushort_t* encWh = (ushort_t*)carve(p, (size_t)IN_DIM * HID * 2);
  ushort_t* encWl = (ushort_t*)carve(p, (size_t)IN_DIM * HID * 2);
  ushort_t* Wl0h  = (ushort_t*)carve(p, (size_t)HID * HID * 2);
  ushort_t* Wl0l  = (ushort_t*)carve(p, (size_t)HID * HID * 2);
  ushort_t* Wr0h  = (ushort_t*)carve(p, (size_t)HID * HID * 2);
  ushort_t* Wr0l  = (ushort_t*)carve(p, (size_t)HID * HID * 2);
  ushort_t* Wl1h  = (ushort_t*)carve(p, (size_t)HID * HID * 2);
  ushort_t* Wl1l  = (ushort_t*)carve(p, (size_t)HID * HID * 2);
  ushort_t* Wr1h  = (ushort_t*)carve(p, (size_t)HID * HID * 2);
  ushort_t* Wr1l  = (ushort_t*)carve(p, (size_t)HID * HID * 2);

  // --- CSR build ---
  hipMemsetAsync(cursor, 0, N_NODES * sizeof(int), stream);
  int eb = 256, eg = (EP + eb - 1) / eb;
  hist_kernel<<<eg, eb, 0, stream>>>(ei, cursor);
  scan_kernel<<<1, 1024, 0, stream>>>(cursor, row_ptr);
  scatter_kernel<<<eg, eb, 0, stream>>>(ei, cursor, csr_src, csr_eid);

  // --- weight preprocessing (transpose + bf16 split) ---
  int wthreads = 256;
  wsplit_kernel<<<(IN_DIM * HID + wthreads - 1) / wthreads, wthreads, 0, stream>>>(enc_W, encWh, encWl, IN_DIM, HID);
  wsplit_kernel<<<(HID * HID + wthreads - 1) / wthreads, wthreads, 0, stream>>>(Wl0, Wl0h, Wl0l, HID, HID);
  wsplit_kernel<<<(HID * HID + wthreads - 1) / wthreads, wthreads, 0, stream>>>(Wr0, Wr0h, Wr0l, HID, HID);
  wsplit_kernel<<<(HID * HID + wthreads - 1) / wthreads, wthreads, 0, stream>>>(Wl1, Wl1h, Wl1l, HID, HID);
  wsplit_kernel<<<(HID * HID + wthreads - 1) / wthreads, wthreads, 0, stream>>>(Wr1, Wr1h, Wr1l, HID, HID);

  dim3 gGemm((N_NODES + 127) / 128, HID / 128);
  dim3 bGemm(256);

  // encoder: h = x @ enc_W + enc_b
  gemm_mfma<<<gGemm, bGemm, 0, stream>>>(x, encWh, encWl, enc_b, h, N_NODES, IN_DIM, HID);

  // layer 0
  gemm_mfma<<<gGemm, bGemm, 0, stream>>>(h, Wl0h, Wl0l, bl0, xl, N_NODES, HID, HID);
  gemm_mfma<<<gGemm, bGemm, 0, stream>>>(h, Wr0h, Wr0l, br0, xr, N_NODES, HID, HID);
  gat_layer<<<N_NODES, 64, 0, stream>>>(xl, xr, h, att0, bias0, row_ptr, csr_src, csr_eid, logits, alpha0);

  // layer 1
  gemm_mfma<<<gGemm, bGemm, 0, stream>>>(h, Wl1h, Wl1l, bl1, xl, N_NODES, HID, HID);
  gemm_mfma<<<gGemm, bGemm, 0, stream>>>(h, Wr1h, Wr1l, br1, xr, N_NODES, HID, HID);
  gat_layer<<<N_NODES, 64, 0, stream>>>(xl, xr, h, att1, bias1, row_ptr, csr_src, csr_eid, logits, alpha1);

  // classifier
  clf_kernel<<<N_NODES, 64, 0, stream>>>(h, clf_W, clf_b, preds);
}

// Round 4
// 1076.009 us; speedup vs baseline: 1.8265x; 1.0642x over previous
//
#include <hip/hip_runtime.h>
#include <hip/hip_bf16.h>
#include <math.h>

// Problem constants (from reference)
#define N_NODES 50000
#define E_EDGES 800000
#define EP (E_EDGES + N_NODES)   // 850000 edges incl. self-loops
#define IN_DIM 1280
#define HID 256
#define NHEAD 4
#define DHEAD 64
#define NEG_SLOPE 0.2f

typedef unsigned short ushort_t;
typedef __attribute__((ext_vector_type(8))) short short8;     // 8 bf16 (4 VGPRs)
typedef __attribute__((ext_vector_type(4))) float floatx4;    // MFMA acc

// truncation split: x = hi + lo + O(2^-16 x)
__device__ __forceinline__ void split_bf16(float x, ushort_t& hi, ushort_t& lo) {
  unsigned u = __float_as_uint(x);
  hi = (ushort_t)(u >> 16);
  float rem = x - __uint_as_float(u & 0xFFFF0000u);
  lo = (ushort_t)(__float_as_uint(rem) >> 16);
}

__device__ __forceinline__ void gload_lds16(const void* g, void* l) {
  __builtin_amdgcn_global_load_lds(
      (const __attribute__((address_space(1))) unsigned int*)g,
      (__attribute__((address_space(3))) unsigned int*)l, 16, 0, 0);
}

// ---------------- graph build (CSR by dst, rebuilt every call) ----------------

__global__ void hist_kernel(const int* __restrict__ ei, int* __restrict__ deg) {
  int e = blockIdx.x * blockDim.x + threadIdx.x;
  if (e >= EP) return;
  int dst = (e < E_EDGES) ? ei[E_EDGES + e] : (e - E_EDGES);
  atomicAdd(&deg[dst], 1);
}

__global__ __launch_bounds__(1024) void scan_kernel(int* __restrict__ dc, int* __restrict__ row_ptr) {
  __shared__ int wsum[16];
  int tid = threadIdx.x;
  int lane = tid & 63;
  int wid = tid >> 6;
  int running = 0;
  if (tid == 0) row_ptr[0] = 0;
  for (int base = 0; base < N_NODES; base += 1024) {
    int i = base + tid;
    int v = (i < N_NODES) ? dc[i] : 0;
    int s = v;
    #pragma unroll
    for (int off = 1; off < 64; off <<= 1) {
      int t = __shfl_up(s, off);
      if (lane >= off) s += t;
    }
    if (lane == 63) wsum[wid] = s;
    __syncthreads();
    if (wid == 0 && lane < 16) {
      int w = wsum[lane];
      #pragma unroll
      for (int off = 1; off < 16; off <<= 1) {
        int t = __shfl_up(w, off);
        if (lane >= off) w += t;
      }
      wsum[lane] = w;
    }
    __syncthreads();
    int woff = (wid > 0) ? wsum[wid - 1] : 0;
    int incl = running + woff + s;
    if (i < N_NODES) {
      row_ptr[i + 1] = incl;
      dc[i] = incl - v;
    }
    running += wsum[15];
    __syncthreads();
  }
}

__global__ void scatter_kernel(const int* __restrict__ ei, int* __restrict__ cursor,
                               int* __restrict__ csr_src, int* __restrict__ csr_eid) {
  int e = blockIdx.x * blockDim.x + threadIdx.x;
  if (e >= EP) return;
  int src, dst;
  if (e < E_EDGES) { src = ei[e]; dst = ei[E_EDGES + e]; }
  else             { src = dst = e - E_EDGES; }
  int pos = atomicAdd(&cursor[dst], 1);
  csr_src[pos] = src;
  csr_eid[pos] = e;
}

// ---------------- weight split into k-chunk-packed layout ----------------
// P[((k>>3)*NcT + colOff + n)*8 + (k&7)] = split(W[k][n]).
// A (bn,k0) B-tile is then 128 cols x 32 k of contiguous 16B-per-(col,sub) chunks:
// entry e in [0,512): sub=e>>7, col=e&127 -> global ((k0>>3)+sub)*NcT + bn + col (x8 elems),
// lane-contiguous for global_load_lds AND bank-conflict-free for frag reads.
__global__ void wsplit_packed(const float* __restrict__ W, ushort_t* __restrict__ Ph,
                              ushort_t* __restrict__ Pl, int K, int Nc, int NcT, int colOff) {
  int idx = blockIdx.x * blockDim.x + threadIdx.x;
  if (idx >= K * Nc) return;
  int k = idx / Nc, n = idx - k * Nc;
  ushort_t hi, lo;
  split_bf16(W[idx], hi, lo);
  size_t pi = ((size_t)(k >> 3) * NcT + colOff + n) * 8 + (k & 7);
  Ph[pi] = hi;
  Pl[pi] = lo;
}

// ---------------- MFMA GEMM: C[M, 0..NcT) = A[M,K](fp32) @ W + bias ----------------
// 64x128 tile, BK=32, 4 waves (2x2, each 32x64 via 2x4 mfma_f32_16x16x32_bf16).
// A: fp32 global -> in-register 3-term bf16 split -> padded LDS (stride 40 bf16, 2-way banks).
// B: packed bf16 via global_load_lds (k-chunk layout, 2-way banks).
// Column-split epilogue: col < Nsplit -> C_l/bias_l, else C_r/bias_r (fused Wl|Wr GEMMs).
__global__ __launch_bounds__(256, 4) void gemm64(const float* __restrict__ A,
                                                 const ushort_t* __restrict__ Bh,
                                                 const ushort_t* __restrict__ Bl,
                                                 const float* __restrict__ bias_l,
                                                 const float* __restrict__ bias_r,
                                                 float* __restrict__ C_l,
                                                 float* __restrict__ C_r,
                                                 int M, int K, int NcT, int Nsplit) {
  __shared__ ushort_t sAh[64 * 40];   // padded: row stride 40 bf16 (80 B)
  __shared__ ushort_t sAl[64 * 40];
  __shared__ ushort_t sBh[128 * 32];  // [sub_k][col] packed: elem (sub*128+col)*8
  __shared__ ushort_t sBl[128 * 32];

  const int tid = threadIdx.x;
  const int lane = tid & 63;
  const int w = tid >> 6;
  const int wm = w >> 1, wn = w & 1;  // 2x2 wave grid: rows wm*32, cols wn*64
  const int bm = blockIdx.x * 64;
  const int bn = blockIdx.y * 128;
  const int r = lane & 15, q = lane >> 4;

  floatx4 acc[2][4];
  #pragma unroll
  for (int i = 0; i < 2; ++i)
    #pragma unroll
    for (int j = 0; j < 4; ++j) acc[i][j] = (floatx4)(0.0f);

  // A staging: thread -> row=tid>>2 (64 rows), chunk=tid&3 (8 floats each)
  const int arow = tid >> 2, achunk = tid & 3;
  int ag = bm + arow; if (ag >= M) ag = M - 1;   // clamp; garbage rows never stored
  const float* aptr = A + (size_t)ag * K + achunk * 8;
  const int awoff = arow * 40 + achunk * 8;

  // B staging: entries e0=tid, e1=tid+256 of 512 x 16B per half
  const int e0 = tid, e1 = tid + 256;
  const size_t b0base = ((size_t)(e0 >> 7) * NcT + bn + (e0 & 127)) * 8;
  const size_t b1base = ((size_t)(e1 >> 7) * NcT + bn + (e1 & 127)) * 8;

  for (int k0 = 0; k0 < K; k0 += 32) {
    // async B (packed layout: advance by (k0>>3)*NcT*8 elems)
    size_t kadd = (size_t)(k0 >> 3) * NcT * 8;
    gload_lds16(Bh + b0base + kadd, &sBh[e0 * 8]);
    gload_lds16(Bh + b1base + kadd, &sBh[e1 * 8]);
    gload_lds16(Bl + b0base + kadd, &sBl[e0 * 8]);
    gload_lds16(Bl + b1base + kadd, &sBl[e1 * 8]);

    // A: 8 fp32 -> split -> LDS
    float va[8];
    *(float4*)&va[0] = *(const float4*)(aptr + k0);
    *(float4*)&va[4] = *(const float4*)(aptr + k0 + 4);
    short8 hv, lv;
    #pragma unroll
    for (int i = 0; i < 8; ++i) {
      ushort_t hi, lo;
      split_bf16(va[i], hi, lo);
      hv[i] = (short)hi; lv[i] = (short)lo;
    }
    *(short8*)&sAh[awoff] = hv;
    *(short8*)&sAl[awoff] = lv;

    __syncthreads();

    short8 ah[2], al[2], bh[4], bl[4];
    #pragma unroll
    for (int i = 0; i < 2; ++i) {
      int off = (wm * 32 + i * 16 + r) * 40 + q * 8;
      ah[i] = *(const short8*)&sAh[off];
      al[i] = *(const short8*)&sAl[off];
    }
    #pragma unroll
    for (int j = 0; j < 4; ++j) {
      int off = (q * 128 + wn * 64 + j * 16 + r) * 8;
      bh[j] = *(const short8*)&sBh[off];
      bl[j] = *(const short8*)&sBl[off];
    }
    #pragma unroll
    for (int i = 0; i < 2; ++i)
      #pragma unroll
      for (int j = 0; j < 4; ++j) {
        acc[i][j] = __builtin_amdgcn_mfma_f32_16x16x32_bf16(ah[i], bh[j], acc[i][j], 0, 0, 0);
        acc[i][j] = __builtin_amdgcn_mfma_f32_16x16x32_bf16(ah[i], bl[j], acc[i][j], 0, 0, 0);
        acc[i][j] = __builtin_amdgcn_mfma_f32_16x16x32_bf16(al[i], bh[j], acc[i][j], 0, 0, 0);
      }
    __syncthreads();
  }

  // epilogue: C/D layout col=lane&15, row=(lane>>4)*4+reg
  #pragma unroll
  for (int j = 0; j < 4; ++j) {
    int cg = bn + wn * 64 + j * 16 + r;
    bool sec = cg >= Nsplit;
    int cc = sec ? cg - Nsplit : cg;
    float bv = sec ? bias_r[cc] : bias_l[cc];
    float* Cb = sec ? C_r : C_l;
    #pragma unroll
    for (int i = 0; i < 2; ++i) {
      int row0 = bm + wm * 32 + i * 16 + q * 4;
      #pragma unroll
      for (int rr = 0; rr < 4; ++rr) {
        int row = row0 + rr;
        if (row < M) Cb[(size_t)row * HID + cc] = acc[i][j][rr] + bv;
      }
    }
  }
}

// ---------------- GATv2 layer: one wave per destination node, single-gather ----------------
__global__ __launch_bounds__(64) void gat_layer(const float* __restrict__ xl,
                                                const float* __restrict__ xr,
                                                float* h_inout,
                                                const float* __restrict__ att,
                                                const float* __restrict__ bias,
                                                const int* __restrict__ row_ptr,
                                                const int* __restrict__ csr_src,
                                                const int* __restrict__ csr_eid,
                                                float* __restrict__ logits_ws,
                                                float* __restrict__ alpha_out) {
  int node = blockIdx.x;
  int l = threadIdx.x;
  int hgrp = l >> 4;
  int r0 = row_ptr[node];
  int r1 = row_ptr[node + 1];

  float4 xr4 = *(const float4*)(xr + (size_t)node * HID + l * 4);
  float4 at4 = *(const float4*)(att + l * 4);

  float m = -INFINITY;
  float den = 0.f;
  float4 acc = make_float4(0.f, 0.f, 0.f, 0.f);
  for (int j = r0; j < r1; ++j) {
    int s = csr_src[j];
    float4 v = *(const float4*)(xl + (size_t)s * HID + l * 4);
    float t0 = v.x + xr4.x; t0 = (t0 > 0.f) ? t0 : NEG_SLOPE * t0;
    float t1 = v.y + xr4.y; t1 = (t1 > 0.f) ? t1 : NEG_SLOPE * t1;
    float t2 = v.z + xr4.z; t2 = (t2 > 0.f) ? t2 : NEG_SLOPE * t2;
    float t3 = v.w + xr4.w; t3 = (t3 > 0.f) ? t3 : NEG_SLOPE * t3;
    float p = t0 * at4.x + t1 * at4.y + t2 * at4.z + t3 * at4.w;
    p += __shfl_xor(p, 1);
    p += __shfl_xor(p, 2);
    p += __shfl_xor(p, 4);
    p += __shfl_xor(p, 8);
    if ((l & 15) == 0) logits_ws[(size_t)j * NHEAD + hgrp] = p;
    float m_new = fmaxf(m, p);
    float scale = __expf(m - m_new);
    float wgt = __expf(p - m_new);
    den = den * scale + wgt;
    acc.x = acc.x * scale + wgt * v.x;
    acc.y = acc.y * scale + wgt * v.y;
    acc.z = acc.z * scale + wgt * v.z;
    acc.w = acc.w * scale + wgt * v.w;
    m = m_new;
  }
  float inv_den = 1.f / (den + 1e-16f);

  float4 b4 = *(const float4*)(bias + l * 4);
  float4 h4 = *(const float4*)(h_inout + (size_t)node * HID + l * 4);
  float o0 = acc.x * inv_den + b4.x + h4.x;
  float o1 = acc.y * inv_den + b4.y + h4.y;
  float o2 = acc.z * inv_den + b4.z + h4.z;
  float o3 = acc.w * inv_den + b4.w + h4.w;
  o0 = (o0 > 0.f) ? o0 : (__expf(o0) - 1.f);
  o1 = (o1 > 0.f) ? o1 : (__expf(o1) - 1.f);
  o2 = (o2 > 0.f) ? o2 : (__expf(o2) - 1.f);
  o3 = (o3 > 0.f) ? o3 : (__expf(o3) - 1.f);
  *(float4*)(h_inout + (size_t)node * HID + l * 4) = make_float4(o0, o1, o2, o3);

  __threadfence_block();

  float mh = __shfl(m, (l & 3) * 16);
  float dh = __shfl(den, (l & 3) * 16);
  float invd = 1.f / (dh + 1e-16f);
  for (int j = r0 + (l >> 2); j < r1; j += 16) {
    float lg = logits_ws[(size_t)j * NHEAD + (l & 3)];
    alpha_out[(size_t)csr_eid[j] * NHEAD + (l & 3)] = __expf(lg - mh) * invd;
  }
}

// ---------------- classifier ----------------
__global__ __launch_bounds__(64) void clf_kernel(const float* __restrict__ h,
                                                 const float* __restrict__ clf_W,
                                                 const float* __restrict__ clf_b,
                                                 float* __restrict__ preds) {
  int n = blockIdx.x;
  int l = threadIdx.x;
  float4 v = *(const float4*)(h + (size_t)n * HID + l * 4);
  float4 w = *(const float4*)(clf_W + l * 4);
  float s = v.x * w.x + v.y * w.y + v.z * w.z + v.w * w.w;
  s += __shfl_xor(s, 1);
  s += __shfl_xor(s, 2);
  s += __shfl_xor(s, 4);
  s += __shfl_xor(s, 8);
  s += __shfl_xor(s, 16);
  s += __shfl_xor(s, 32);
  if (l == 0) preds[n] = s + clf_b[0];
}

// ---------------- launcher ----------------
static inline char* carve(char*& p, size_t bytes) {
  char* ret = p;
  p += (bytes + 255) & ~(size_t)255;
  return ret;
}

extern "C" void kernel_launch(void* const* d_in, const int* in_sizes, int n_in,
                              void* d_out, int out_size, void* d_ws, size_t ws_size,
                              hipStream_t stream) {
  const float* x     = (const float*)d_in[0];
  const int*   ei    = (const int*)d_in[1];
  const float* enc_W = (const float*)d_in[2];
  const float* enc_b = (const float*)d_in[3];
  const float* Wl0   = (const float*)d_in[4];
  const float* bl0   = (const float*)d_in[5];
  const float* Wr0   = (const float*)d_in[6];
  const float* br0   = (const float*)d_in[7];
  const float* att0  = (const float*)d_in[8];
  const float* bias0 = (const float*)d_in[9];
  const float* Wl1   = (const float*)d_in[10];
  const float* bl1   = (const float*)d_in[11];
  const float* Wr1   = (const float*)d_in[12];
  const float* br1   = (const float*)d_in[13];
  const float* att1  = (const float*)d_in[14];
  const float* bias1 = (const float*)d_in[15];
  const float* clf_W = (const float*)d_in[16];
  const float* clf_b = (const float*)d_in[17];

  float* preds  = (float*)d_out;
  float* alpha0 = preds + N_NODES;
  float* alpha1 = alpha0 + (size_t)EP * NHEAD;

  char* p = (char*)d_ws;
  float* h      = (float*)carve(p, (size_t)N_NODES * HID * 4);
  float* xl     = (float*)carve(p, (size_t)N_NODES * HID * 4);
  float* xr     = (float*)carve(p, (size_t)N_NODES * HID * 4);
  float* logits = (float*)carve(p, (size_t)EP * NHEAD * 4);
  int* row_ptr  = (int*)carve(p, (size_t)(N_NODES + 1) * 4);
  int* cursor   = (int*)carve(p, (size_t)N_NODES * 4);
  int* csr_src  = (int*)carve(p, (size_t)EP * 4);
  int* csr_eid  = (int*)carve(p, (size_t)EP * 4);
  ushort_t* encPh = (ushort_t*)carve(p, (size_t)IN_DIM * HID * 2);
  ushort_t* encPl = (ushort_t*)carve(p, (size_t)IN_DIM * HID * 2);
  ushort_t* P0h   = (ushort_t*)carve(p, (size_t)HID * 512 * 2);
  ushort_t* P0l   = (ushort_t*)carve(p, (size_t)HID * 512 * 2);
  ushort_t* P1h   = (ushort_t*)carve(p, (size_t)HID * 512 * 2);
  ushort_t* P1l   = (ushort_t*)carve(p, (size_t)HID * 512 * 2);

  // --- CSR build ---
  hipMemsetAsync(cursor, 0, N_NODES * sizeof(int), stream);
  int eb = 256, eg = (EP + eb - 1) / eb;
  hist_kernel<<<eg, eb, 0, stream>>>(ei, cursor);
  scan_kernel<<<1, 1024, 0, stream>>>(cursor, row_ptr);
  scatter_kernel<<<eg, eb, 0, stream>>>(ei, cursor, csr_src, csr_eid);

  // --- weight preprocessing: packed split. Layer weights concat [Wl | Wr] along cols ---
  int wt = 256;
  wsplit_packed<<<(IN_DIM * HID + wt - 1) / wt, wt, 0, stream>>>(enc_W, encPh, encPl, IN_DIM, HID, HID, 0);
  wsplit_packed<<<(HID * HID + wt - 1) / wt, wt, 0, stream>>>(Wl0, P0h, P0l, HID, HID, 512, 0);
  wsplit_packed<<<(HID * HID + wt - 1) / wt, wt, 0, stream>>>(Wr0, P0h, P0l, HID, HID, 512, 256);
  wsplit_packed<<<(HID * HID + wt - 1) / wt, wt, 0, stream>>>(Wl1, P1h, P1l, HID, HID, 512, 0);
  wsplit_packed<<<(HID * HID + wt - 1) / wt, wt, 0, stream>>>(Wr1, P1h, P1l, HID, HID, 512, 256);

  const int MB = (N_NODES + 63) / 64;   // 782
  dim3 bGemm(256);

  // encoder: h = x @ enc_W + enc_b   (NcT=256, all cols -> h)
  gemm64<<<dim3(MB, 2), bGemm, 0, stream>>>(x, encPh, encPl, enc_b, enc_b, h, h,
                                            N_NODES, IN_DIM, HID, HID);

  // layer 0: fused xl|xr = h @ [Wl0|Wr0]
  gemm64<<<dim3(MB, 4), bGemm, 0, stream>>>(h, P0h, P0l, bl0, br0, xl, xr,
                                            N_NODES, HID, 512, HID);
  gat_layer<<<N_NODES, 64, 0, stream>>>(xl, xr, h, att0, bias0, row_ptr, csr_src, csr_eid, logits, alpha0);

  // layer 1
  gemm64<<<dim3(MB, 4), bGemm, 0, stream>>>(h, P1h, P1l, bl1, br1, xl, xr,
                                            N_NODES, HID, 512, HID);
  gat_layer<<<N_NODES, 64, 0, stream>>>(xl, xr, h, att1, bias1, row_ptr, csr_src, csr_eid, logits, alpha1);

  // classifier
  clf_kernel<<<N_NODES, 64, 0, stream>>>(h, clf_W, clf_b, preds);
}